// Round 15
// baseline (142.682 us; speedup 1.0000x reference)
//
#include <hip/hip_runtime.h>
#include <hip/hip_bf16.h>

typedef __attribute__((ext_vector_type(8))) short short8;
typedef __attribute__((ext_vector_type(4))) float floatx4;

#define NSEQ   2048
#define DMODEL 1024
#define NHEAD  16
#define HDIM   64
#define BATCH  2
#define LOG2E 1.44269504088896340736f

#define XF4   1048576u     // float4 count per x tensor (2*2048*1024/4)
#define WF4   262144u      // float4 count per weight  (1024*1024/4)

__device__ __forceinline__ void gload16(const void* g, void* l) {
    __builtin_amdgcn_global_load_lds(
        (const __attribute__((address_space(1))) void*)g,
        (__attribute__((address_space(3))) void*)l, 16, 0, 0);
}

#define BARRIER() asm volatile("s_barrier" ::: "memory")
#define CFENCE()  asm volatile("" ::: "memory")

__device__ __forceinline__ float bf16lo(unsigned u) {
    union { unsigned i; float f; } c; c.i = u << 16; return c.f;
}
__device__ __forceinline__ float bf16hi(unsigned u) {
    union { unsigned i; float f; } c; c.i = u & 0xffff0000u; return c.f;
}

// ---------------------------------------------------------------------------
// Pre-convert all f32 operands to bf16 (makes every GEMM staging a pure copy)
// ---------------------------------------------------------------------------
__global__ __launch_bounds__(256)
void cvt_all(const float* __restrict__ xq, const float* __restrict__ xkv,
             const float* __restrict__ wq, const float* __restrict__ wk,
             const float* __restrict__ wv, const float* __restrict__ wo,
             __hip_bfloat16* __restrict__ dxq, __hip_bfloat16* __restrict__ dxkv,
             __hip_bfloat16* __restrict__ dwq, __hip_bfloat16* __restrict__ dwk,
             __hip_bfloat16* __restrict__ dwv, __hip_bfloat16* __restrict__ dwo)
{
    const unsigned total = 2*XF4 + 4*WF4;
    const unsigned stride = gridDim.x * blockDim.x;
    for (unsigned i = blockIdx.x*blockDim.x + threadIdx.x; i < total; i += stride) {
        const float4* src; __hip_bfloat16* dst; unsigned off;
        if (i < XF4)        { src = (const float4*)xq;  dst = dxq;  off = i; }
        else if (i < 2*XF4) { src = (const float4*)xkv; dst = dxkv; off = i - XF4; }
        else {
            unsigned j = i - 2*XF4; unsigned ws = j >> 18; off = j & (WF4 - 1);
            src = (const float4*)(ws==0 ? wq : ws==1 ? wk : ws==2 ? wv : wo);
            dst = (ws==0 ? dwq : ws==1 ? dwk : ws==2 ? dwv : dwo);
        }
        float4 v = src[off];
        __hip_bfloat16 h[4] = {__float2bfloat16(v.x), __float2bfloat16(v.y),
                               __float2bfloat16(v.z), __float2bfloat16(v.w)};
        *reinterpret_cast<uint2*>(dst + (size_t)off*4) = *reinterpret_cast<uint2*>(h);
    }
}

// bias f32 [N][N] -> bf16 * LOG2E (prescaled for exp2-domain softmax)
__global__ __launch_bounds__(256)
void cvt_bias(const float* __restrict__ src, __hip_bfloat16* __restrict__ dst)
{
    const unsigned total = (unsigned)(NSEQ*(size_t)NSEQ/4);
    const unsigned stride = gridDim.x * blockDim.x;
    for (unsigned i = blockIdx.x*blockDim.x + threadIdx.x; i < total; i += stride) {
        float4 v = ((const float4*)src)[i];
        __hip_bfloat16 h[4] = {__float2bfloat16(v.x * LOG2E), __float2bfloat16(v.y * LOG2E),
                               __float2bfloat16(v.z * LOG2E), __float2bfloat16(v.w * LOG2E)};
        *reinterpret_cast<uint2*>(dst + (size_t)i*4) = *reinterpret_cast<uint2*>(h);
    }
}

// ---------------------------------------------------------------------------
// Fused QKV GEMM (round-8 verified version, verbatim)
// ---------------------------------------------------------------------------
struct QkvArgs {
    const __hip_bfloat16* A[3];
    const __hip_bfloat16* W[3];
    const float*          bias[3];
    __hip_bfloat16*       out[3];
};

__global__ __launch_bounds__(256)
void qkv_gemm(QkvArgs args)
{
    __shared__ __hip_bfloat16 S[256][72];

    const int tid  = threadIdx.x;
    const int lane = tid & 63;
    const int wv   = tid >> 6;
    const int wm   = wv >> 1, wn = wv & 1;
    const int l15  = lane & 15, l4 = lane >> 4;
    const int m0   = blockIdx.x * 128;
    const int n0   = blockIdx.y * 128;
    const int z    = blockIdx.z;

    const __hip_bfloat16* __restrict__ A = args.A[z];
    const __hip_bfloat16* __restrict__ W = args.W[z];

    floatx4 acc[4][4] = {};

    for (int k0 = 0; k0 < DMODEL; k0 += 64) {
        #pragma unroll
        for (int it = 0; it < 4; ++it) {
            const int sI   = tid + 256 * it;
            const int row  = sI >> 2;
            const int colq = (sI & 3) * 16;
            const __hip_bfloat16* src = (it < 2)
                ? A + (size_t)(m0 + row) * DMODEL + k0 + colq
                : W + (size_t)(n0 + row - 128) * DMODEL + k0 + colq;
            const uint4* s4 = reinterpret_cast<const uint4*>(src);
            *reinterpret_cast<uint4*>(&S[row][colq])     = s4[0];
            *reinterpret_cast<uint4*>(&S[row][colq + 8]) = s4[1];
        }
        __syncthreads();

        #pragma unroll
        for (int kk = 0; kk < 64; kk += 32) {
            short8 af[4], bf[4];
            #pragma unroll
            for (int mi = 0; mi < 4; ++mi)
                af[mi] = *reinterpret_cast<const short8*>(&S[wm*64 + mi*16 + l15][kk + l4*8]);
            #pragma unroll
            for (int nj = 0; nj < 4; ++nj)
                bf[nj] = *reinterpret_cast<const short8*>(&S[128 + wn*64 + nj*16 + l15][kk + l4*8]);
            #pragma unroll
            for (int mi = 0; mi < 4; ++mi)
                #pragma unroll
                for (int nj = 0; nj < 4; ++nj)
                    acc[mi][nj] = __builtin_amdgcn_mfma_f32_16x16x32_bf16(
                        af[mi], bf[nj], acc[mi][nj], 0, 0, 0);
        }
        __syncthreads();
    }

    const float* bias = args.bias[z];
    __hip_bfloat16* C = args.out[z];
    const bool vt = (z == 2);
    #pragma unroll
    for (int mi = 0; mi < 4; ++mi) {
        const int mbase = m0 + wm*64 + mi*16 + l4*4;
        #pragma unroll
        for (int nj = 0; nj < 4; ++nj) {
            const int nn = n0 + wn*64 + nj*16 + l15;
            const float bb = bias[nn];
            const int h = nn >> 6, d = nn & (HDIM - 1);
            #pragma unroll
            for (int r = 0; r < 4; ++r) {
                const int m = mbase + r;
                const int b = m >> 11, n = m & (NSEQ - 1);
                const float val = acc[mi][nj][r] + bb;
                if (!vt)
                    C[((size_t)(b*NHEAD + h) * NSEQ + n) * HDIM + d] = __float2bfloat16(val);
                else
                    C[((size_t)(b*NHEAD + h) * HDIM + d) * NSEQ + n] = __float2bfloat16(val);
            }
        }
    }
}

// ---------------------------------------------------------------------------
// O-projection GEMM (round-8 version): BM=64, BN=128. f32 output.
// ---------------------------------------------------------------------------
__global__ __launch_bounds__(256)
void oproj_gemm(const __hip_bfloat16* __restrict__ A, const __hip_bfloat16* __restrict__ W,
                const float* __restrict__ bias, float* __restrict__ C)
{
    __shared__ __hip_bfloat16 S[192][72];

    const int tid  = threadIdx.x;
    const int lane = tid & 63;
    const int wv   = tid >> 6;
    const int l15  = lane & 15, l4 = lane >> 4;
    const int m0   = blockIdx.x * 64;
    const int n0   = blockIdx.y * 128;

    floatx4 acc[4][2] = {};

    for (int k0 = 0; k0 < DMODEL; k0 += 64) {
        #pragma unroll
        for (int it = 0; it < 3; ++it) {
            const int sI   = tid + 256 * it;
            const int row  = sI >> 2;
            const int colq = (sI & 3) * 16;
            const __hip_bfloat16* src = (it < 1)
                ? A + (size_t)(m0 + row) * DMODEL + k0 + colq
                : W + (size_t)(n0 + row - 64) * DMODEL + k0 + colq;
            const uint4* s4 = reinterpret_cast<const uint4*>(src);
            *reinterpret_cast<uint4*>(&S[row][colq])     = s4[0];
            *reinterpret_cast<uint4*>(&S[row][colq + 8]) = s4[1];
        }
        __syncthreads();

        #pragma unroll
        for (int kk = 0; kk < 64; kk += 32) {
            short8 af[4], bf[2];
            #pragma unroll
            for (int mi = 0; mi < 4; ++mi)
                af[mi] = *reinterpret_cast<const short8*>(&S[mi*16 + l15][kk + l4*8]);
            #pragma unroll
            for (int nj = 0; nj < 2; ++nj)
                bf[nj] = *reinterpret_cast<const short8*>(&S[64 + wv*32 + nj*16 + l15][kk + l4*8]);
            #pragma unroll
            for (int mi = 0; mi < 4; ++mi)
                #pragma unroll
                for (int nj = 0; nj < 2; ++nj)
                    acc[mi][nj] = __builtin_amdgcn_mfma_f32_16x16x32_bf16(
                        af[mi], bf[nj], acc[mi][nj], 0, 0, 0);
        }
        __syncthreads();
    }

    #pragma unroll
    for (int mi = 0; mi < 4; ++mi) {
        const int mbase = m0 + mi*16 + l4*4;
        #pragma unroll
        for (int nj = 0; nj < 2; ++nj) {
            const int nn = n0 + wv*32 + nj*16 + l15;
            const float bb = bias[nn];
            #pragma unroll
            for (int r = 0; r < 4; ++r)
                C[(size_t)(mbase + r) * DMODEL + nn] = acc[mi][nj][r] + bb;
        }
    }
}

// ---------------------------------------------------------------------------
// Flash attention v13 = v12 with SHARED per-wave PL buffer (one 2KB tile,
// used sequentially by group0 then group1; same-wave LDS ops execute in
// order -> no hazard). LDS 80KB -> 72KB so 2 blocks/CU actually fit
// (v12's 80KB silently fell to 1 block/CU -> occupancy 12%). Everything
// else identical to v12: 32 q-rows/wave, K/V frags read once and reused,
// v8 dbuf skeleton (8 gloads/stage, vmcnt(8)/vmcnt(0), raw s_barrier),
// perm-balanced causal blocks (co-resident pair sums to 34 iters).
// ---------------------------------------------------------------------------
__global__ __launch_bounds__(256, 2)
void flash_attn(const __hip_bfloat16* __restrict__ Q,
                const __hip_bfloat16* __restrict__ K,
                const __hip_bfloat16* __restrict__ VT,
                const __hip_bfloat16* __restrict__ Bb,   // bf16 bias * LOG2E
                const int* __restrict__ selfp,
                const int* __restrict__ causalp,
                __hip_bfloat16* __restrict__ Oout)
{
    __shared__ __align__(16) char KB[2][8192];
    __shared__ __align__(16) char VB[2][8192];
    __shared__ __align__(16) char BBUF[2][16384];
    __shared__ __align__(16) char PL[4][2048];   // per-wave, shared by both groups

    const int tid  = threadIdx.x;
    const int lane = tid & 63;
    const int wv   = tid >> 6;
    const int l15  = lane & 15, l4 = lane >> 4;

    const int g   = blockIdx.x;
    const int bh  = g & 31;            // g&7 = XCD id
    const int ip  = g >> 5;            // [0,16)
    const int t   = (ip < 8) ? ip : 23 - ip;   // perm: pairs (i,i+8) sum to 15
    const int h   = bh & (NHEAD - 1);
    const int b   = bh >> 4;

    const int selfF   = selfp[0];
    const int causalF = causalp[0];
    const bool cz      = (selfF != 0) && (causalF != 0);
    const bool alibiOn = (selfF != 0) && (causalF == 0);
    const float slopeL2 = exp2f(-(8.0f / NHEAD) * (float)(h + 1)) * LOG2E;

    const char* Kh = (const char*)(K  + (size_t)bh * NSEQ * HDIM);
    const char* Vh = (const char*)(VT + (size_t)bh * HDIM * NSEQ);
    const __hip_bfloat16* Qh = Q + (size_t)bh * NSEQ * HDIM;

    const int NT = cz ? (2*t + 2) : (NSEQ/64);

    // Q fragments, both groups (B-operand: col = q = l15, k = d)
    const int q0g = t*128 + wv*16;          // group0 global q base
    const int q1g = q0g + 64;               // group1
    const short8 qf00 = *(const short8*)&Qh[(q0g + l15)*HDIM + l4*8];
    const short8 qf01 = *(const short8*)&Qh[(q0g + l15)*HDIM + 32 + l4*8];
    const short8 qf10 = *(const short8*)&Qh[(q1g + l15)*HDIM + l4*8];
    const short8 qf11 = *(const short8*)&Qh[(q1g + l15)*HDIM + 32 + l4*8];
    CFENCE();

    const int srow = lane >> 3;                  // 0..7
    const int co   = (((lane & 7) ^ srow) << 4); // pre-swizzled col byte

    const char* Bh = (const char*)Bb + (size_t)(t*128) * (NSEQ*2);

    auto stage = [&](int jt, int bi) {
        const int j0 = jt << 6;
        #pragma unroll
        for (int i2 = 0; i2 < 2; ++i2) {
            const int rl = wv*16 + i2*8 + srow;
            const int db = (wv*16 + i2*8) * 128;
            gload16(Kh + (size_t)(j0 + rl)*128 + co,          &KB[bi][db]);
            gload16(Vh + (size_t)rl*4096 + (size_t)j0*2 + co, &VB[bi][db]);
        }
        #pragma unroll
        for (int i2 = 0; i2 < 4; ++i2) {
            const int rb = wv*32 + i2*8 + srow;
            const int db = (wv*32 + i2*8) * 128;
            gload16(Bh + (size_t)rb*4096 + (size_t)j0*2 + co, &BBUF[bi][db]);
        }
    };

    char* plw = &PL[wv][l15 * 128];
    const int swq = (l15 & 7) << 4;
    const int rowb0 = wv*16 + l15;               // group0 row in 128-row bias tile
    const int rowb1 = 64 + wv*16 + l15;          // group1
    const int swb0 = (rowb0 & 7) << 4;
    const int swb1 = (rowb1 & 7) << 4;

    floatx4 o0[4] = {}, o1[4] = {};
    float lr0 = 0.f, lr1 = 0.f;

    stage(0, 0);
    CFENCE();
    int cur = 0;
    for (int jt = 0; jt < NT; ++jt) {
        if (jt + 1 < NT) {
            stage(jt + 1, cur ^ 1);
            asm volatile("s_waitcnt vmcnt(8)" ::: "memory");  // drain stage(jt)
        } else {
            asm volatile("s_waitcnt vmcnt(0)" ::: "memory");
        }
        BARRIER();

        const char* kb = KB[cur];
        const char* vb = VB[cur];
        const char* bb = BBUF[cur];

        const bool g0act = !cz || (jt <= 2*t);

        // ---- K frags: read ONCE, reused for both groups ----
        short8 kf0[4], kf1[4];
        #pragma unroll
        for (int tt = 0; tt < 4; ++tt) {
            const int row = tt*16 + l15;
            const int sw  = (row & 7) << 4;
            kf0[tt] = *(const short8*)(kb + ((row*128 + l4*16)      ^ sw));
            kf1[tt] = *(const short8*)(kb + ((row*128 + 64 + l4*16) ^ sw));
        }

        // ---- QK^T swapped, both groups ----
        floatx4 s40[4], s41[4];
        __builtin_amdgcn_s_setprio(1);
        if (g0act) {
            #pragma unroll
            for (int tt = 0; tt < 4; ++tt) {
                floatx4 z = {};
                z       = __builtin_amdgcn_mfma_f32_16x16x32_bf16(kf0[tt], qf00, z, 0, 0, 0);
                s40[tt] = __builtin_amdgcn_mfma_f32_16x16x32_bf16(kf1[tt], qf01, z, 0, 0, 0);
            }
        }
        #pragma unroll
        for (int tt = 0; tt < 4; ++tt) {
            floatx4 z = {};
            z       = __builtin_amdgcn_mfma_f32_16x16x32_bf16(kf0[tt], qf10, z, 0, 0, 0);
            s41[tt] = __builtin_amdgcn_mfma_f32_16x16x32_bf16(kf1[tt], qf11, z, 0, 0, 0);
        }
        __builtin_amdgcn_s_setprio(0);

        // ---- V frags: read ONCE, reused for both groups ----
        short8 vfA[4], vfB[4];
        #pragma unroll
        for (int dt = 0; dt < 4; ++dt) {
            const int row = dt*16 + l15;
            const int sw  = (row & 7) << 4;
            vfA[dt] = *(const short8*)(vb + ((row*128 + l4*16)      ^ sw));
            vfB[dt] = *(const short8*)(vb + ((row*128 + 64 + l4*16) ^ sw));
        }

        // ---- group 0 (writes PL, reads frags, PV; then group1 reuses PL) ----
        if (g0act) {
            uint2 bl[4];
            #pragma unroll
            for (int tt = 0; tt < 4; ++tt)
                bl[tt] = *(const uint2*)(bb + ((rowb0*128 + tt*32 + l4*8) ^ swb0));
            const bool domask = cz && (jt == 2*t);
            #pragma unroll
            for (int tt = 0; tt < 4; ++tt) {
                float bf[4];
                bf[0] = bf16lo(bl[tt].x); bf[1] = bf16hi(bl[tt].x);
                bf[2] = bf16lo(bl[tt].y); bf[3] = bf16hi(bl[tt].y);
                float e[4];
                #pragma unroll
                for (int r = 0; r < 4; ++r) {
                    const int jloc = tt*16 + l4*4 + r;
                    float v2 = fmaf(s40[tt][r], 0.125f * LOG2E, bf[r]);
                    if (alibiOn) {
                        const int dd = (jt*64 + jloc) - (q0g + l15);
                        if (dd > 0) v2 = fmaf((float)dd, -slopeL2, v2);
                    }
                    e[r] = __builtin_amdgcn_exp2f(v2);
                    if (domask && jloc > (wv*16 + l15)) e[r] = 0.0f;
                    lr0 += e[r];
                }
                unsigned p0, p1;
                asm("v_cvt_pk_bf16_f32 %0, %1, %2" : "=v"(p0) : "v"(e[0]), "v"(e[1]));
                asm("v_cvt_pk_bf16_f32 %0, %1, %2" : "=v"(p1) : "v"(e[2]), "v"(e[3]));
                uint2 pw; pw.x = p0; pw.y = p1;
                *(uint2*)(plw + ((tt*32 + l4*8) ^ swq)) = pw;
            }
            const short8 pf0 = *(const short8*)(plw + ((l4*16)      ^ swq));
            const short8 pf1 = *(const short8*)(plw + ((64 + l4*16) ^ swq));
            __builtin_amdgcn_s_setprio(1);
            #pragma unroll
            for (int dt = 0; dt < 4; ++dt) {
                o0[dt] = __builtin_amdgcn_mfma_f32_16x16x32_bf16(pf0, vfA[dt], o0[dt], 0, 0, 0);
                o0[dt] = __builtin_amdgcn_mfma_f32_16x16x32_bf16(pf1, vfB[dt], o0[dt], 0, 0, 0);
            }
            __builtin_amdgcn_s_setprio(0);
        }

        // ---- group 1 (reuses the same PL; same-wave LDS ops are in-order) ----
        {
            uint2 bl[4];
            #pragma unroll
            for (int tt = 0; tt < 4; ++tt)
                bl[tt] = *(const uint2*)(bb + ((rowb1*128 + tt*32 + l4*8) ^ swb1));
            const bool domask = cz && (jt == NT - 1);
            #pragma unroll
            for (int tt = 0; tt < 4; ++tt) {
                float bf[4];
                bf[0] = bf16lo(bl[tt].x); bf[1] = bf16hi(bl[tt].x);
                bf[2] = bf16lo(bl[tt].y); bf[3] = bf16hi(bl[tt].y);
                float e[4];
                #pragma unroll
                for (int r = 0; r < 4; ++r) {
                    const int jloc = tt*16 + l4*4 + r;
                    float v2 = fmaf(s41[tt][r], 0.125f * LOG2E, bf[r]);
                    if (alibiOn) {
                        const int dd = (jt*64 + jloc) - (q1g + l15);
                        if (dd > 0) v2 = fmaf((float)dd, -slopeL2, v2);
                    }
                    e[r] = __builtin_amdgcn_exp2f(v2);
                    if (domask && jloc > (wv*16 + l15)) e[r] = 0.0f;
                    lr1 += e[r];
                }
                unsigned p0, p1;
                asm("v_cvt_pk_bf16_f32 %0, %1, %2" : "=v"(p0) : "v"(e[0]), "v"(e[1]));
                asm("v_cvt_pk_bf16_f32 %0, %1, %2" : "=v"(p1) : "v"(e[2]), "v"(e[3]));
                uint2 pw; pw.x = p0; pw.y = p1;
                *(uint2*)(plw + ((tt*32 + l4*8) ^ swq)) = pw;
            }
            const short8 pf0 = *(const short8*)(plw + ((l4*16)      ^ swq));
            const short8 pf1 = *(const short8*)(plw + ((64 + l4*16) ^ swq));
            __builtin_amdgcn_s_setprio(1);
            #pragma unroll
            for (int dt = 0; dt < 4; ++dt) {
                o1[dt] = __builtin_amdgcn_mfma_f32_16x16x32_bf16(pf0, vfA[dt], o1[dt], 0, 0, 0);
                o1[dt] = __builtin_amdgcn_mfma_f32_16x16x32_bf16(pf1, vfB[dt], o1[dt], 0, 0, 0);
            }
            __builtin_amdgcn_s_setprio(0);
        }

        BARRIER();
        cur ^= 1;
    }

    // ---- finalize both groups (no mid-loop writes) ----
    {
        float tt0 = lr0;
        tt0 += __shfl_xor(tt0, 16);
        tt0 += __shfl_xor(tt0, 32);
        #pragma unroll
        for (int r = 0; r < 4; ++r) {
            const float lq  = __shfl(tt0, l4*4 + r);
            const float inv = 1.0f / lq;
            const int n = t*128 + wv*16 + l4*4 + r;
            #pragma unroll
            for (int dt = 0; dt < 4; ++dt)
                Oout[((size_t)(b*NSEQ + n)) * DMODEL + h*HDIM + dt*16 + l15] =
                    __float2bfloat16(o0[dt][r] * inv);
        }
        float tt1 = lr1;
        tt1 += __shfl_xor(tt1, 16);
        tt1 += __shfl_xor(tt1, 32);
        #pragma unroll
        for (int r = 0; r < 4; ++r) {
            const float lq  = __shfl(tt1, l4*4 + r);
            const float inv = 1.0f / lq;
            const int n = t*128 + 64 + wv*16 + l4*4 + r;
            #pragma unroll
            for (int dt = 0; dt < 4; ++dt)
                Oout[((size_t)(b*NSEQ + n)) * DMODEL + h*HDIM + dt*16 + l15] =
                    __float2bfloat16(o1[dt][r] * inv);
        }
    }
}

// ---------------------------------------------------------------------------
extern "C" void kernel_launch(void* const* d_in, const int* in_sizes, int n_in,
                              void* d_out, int out_size, void* d_ws, size_t ws_size,
                              hipStream_t stream)
{
    (void)in_sizes; (void)n_in; (void)out_size; (void)ws_size;
    const float* x_q  = (const float*)d_in[0];
    const float* x_kv = (const float*)d_in[1];
    const float* ab   = (const float*)d_in[2];
    const float* Wq   = (const float*)d_in[3];
    const float* bq   = (const float*)d_in[4];
    const float* Wk   = (const float*)d_in[5];
    const float* bk   = (const float*)d_in[6];
    const float* Wv   = (const float*)d_in[7];
    const float* bv   = (const float*)d_in[8];
    const float* Wo   = (const float*)d_in[9];
    const float* bo   = (const float*)d_in[10];
    const int* selfp   = (const int*)d_in[11];
    const int* causalp = (const int*)d_in[12];

    const size_t XB = (size_t)BATCH * NSEQ * DMODEL * sizeof(__hip_bfloat16); // 8 MiB
    const size_t WB = (size_t)DMODEL * DMODEL * sizeof(__hip_bfloat16);       // 2 MiB
    char* ws = (char*)d_ws;
    __hip_bfloat16* xq_b  = (__hip_bfloat16*)(ws);
    __hip_bfloat16* AO    = (__hip_bfloat16*)(ws);                 // alias (xq_b dead)
    __hip_bfloat16* xkv_b = (__hip_bfloat16*)(ws + XB);
    __hip_bfloat16* ab_b  = (__hip_bfloat16*)(ws + XB);            // alias (xkv_b dead)
    __hip_bfloat16* Wq_b  = (__hip_bfloat16*)(ws + 2*XB);
    __hip_bfloat16* Wk_b  = (__hip_bfloat16*)(ws + 2*XB + WB);
    __hip_bfloat16* Wv_b  = (__hip_bfloat16*)(ws + 2*XB + 2*WB);
    __hip_bfloat16* Wo_b  = (__hip_bfloat16*)(ws + 2*XB + 3*WB);
    __hip_bfloat16* Qb    = (__hip_bfloat16*)(ws + 2*XB + 4*WB);
    __hip_bfloat16* Kb    = (__hip_bfloat16*)(ws + 2*XB + 4*WB + XB);
    __hip_bfloat16* VTb   = (__hip_bfloat16*)(ws + 2*XB + 4*WB + 2*XB);

    cvt_all<<<dim3(2048), dim3(256), 0, stream>>>(
        x_q, x_kv, Wq, Wk, Wv, Wo, xq_b, xkv_b, Wq_b, Wk_b, Wv_b, Wo_b);

    QkvArgs qa;
    qa.A[0] = xq_b;  qa.A[1] = xkv_b; qa.A[2] = xkv_b;
    qa.W[0] = Wq_b;  qa.W[1] = Wk_b;  qa.W[2] = Wv_b;
    qa.bias[0] = bq; qa.bias[1] = bk; qa.bias[2] = bv;
    qa.out[0] = Qb;  qa.out[1] = Kb;  qa.out[2] = VTb;
    qkv_gemm<<<dim3(32, 8, 3), dim3(256), 0, stream>>>(qa);

    cvt_bias<<<dim3(1024), dim3(256), 0, stream>>>(ab, ab_b);

    flash_attn<<<dim3(512), dim3(256), 0, stream>>>(
        Qb, Kb, VTb, ab_b, selfp, causalp, AO);

    oproj_gemm<<<dim3(64, 8), dim3(256), 0, stream>>>(AO, Wo_b, bo, (float*)d_out);
}

// Round 16
// 131.530 us; speedup vs baseline: 1.0848x; 1.0848x over previous
//
#include <hip/hip_runtime.h>
#include <hip/hip_bf16.h>

typedef __attribute__((ext_vector_type(8))) short short8;
typedef __attribute__((ext_vector_type(4))) float floatx4;

#define NSEQ   2048
#define DMODEL 1024
#define NHEAD  16
#define HDIM   64
#define BATCH  2
#define LOG2E 1.44269504088896340736f

#define XF4   1048576u     // float4 count per x tensor (2*2048*1024/4) == bias/4
#define WF4   262144u      // float4 count per weight  (1024*1024/4)

__device__ __forceinline__ void gload16(const void* g, void* l) {
    __builtin_amdgcn_global_load_lds(
        (const __attribute__((address_space(1))) void*)g,
        (__attribute__((address_space(3))) void*)l, 16, 0, 0);
}

#define BARRIER() asm volatile("s_barrier" ::: "memory")
#define CFENCE()  asm volatile("" ::: "memory")

__device__ __forceinline__ float bf16lo(unsigned u) {
    union { unsigned i; float f; } c; c.i = u << 16; return c.f;
}
__device__ __forceinline__ float bf16hi(unsigned u) {
    union { unsigned i; float f; } c; c.i = u & 0xffff0000u; return c.f;
}

// ---------------------------------------------------------------------------
// Pre-convert all f32 operands to bf16 in ONE pass (x_q, x_kv, 4 weights,
// and the attention bias scaled by LOG2E). Bias lands in d_out scratch
// (overwritten by oproj afterwards - deterministic, graph-safe).
// ---------------------------------------------------------------------------
__global__ __launch_bounds__(256)
void cvt_all(const float* __restrict__ xq, const float* __restrict__ xkv,
             const float* __restrict__ wq, const float* __restrict__ wk,
             const float* __restrict__ wv, const float* __restrict__ wo,
             const float* __restrict__ bias,
             __hip_bfloat16* __restrict__ dxq, __hip_bfloat16* __restrict__ dxkv,
             __hip_bfloat16* __restrict__ dwq, __hip_bfloat16* __restrict__ dwk,
             __hip_bfloat16* __restrict__ dwv, __hip_bfloat16* __restrict__ dwo,
             __hip_bfloat16* __restrict__ dbias)
{
    const unsigned total = 3*XF4 + 4*WF4;
    const unsigned stride = gridDim.x * blockDim.x;
    for (unsigned i = blockIdx.x*blockDim.x + threadIdx.x; i < total; i += stride) {
        const float4* src; __hip_bfloat16* dst; unsigned off; float sc = 1.0f;
        if (i < XF4)        { src = (const float4*)xq;  dst = dxq;  off = i; }
        else if (i < 2*XF4) { src = (const float4*)xkv; dst = dxkv; off = i - XF4; }
        else if (i < 2*XF4 + 4*WF4) {
            unsigned j = i - 2*XF4; unsigned ws = j >> 18; off = j & (WF4 - 1);
            src = (const float4*)(ws==0 ? wq : ws==1 ? wk : ws==2 ? wv : wo);
            dst = (ws==0 ? dwq : ws==1 ? dwk : ws==2 ? dwv : dwo);
        } else {
            src = (const float4*)bias; dst = dbias; off = i - (2*XF4 + 4*WF4);
            sc = LOG2E;
        }
        float4 v = src[off];
        __hip_bfloat16 h[4] = {__float2bfloat16(v.x * sc), __float2bfloat16(v.y * sc),
                               __float2bfloat16(v.z * sc), __float2bfloat16(v.w * sc)};
        *reinterpret_cast<uint2*>(dst + (size_t)off*4) = *reinterpret_cast<uint2*>(h);
    }
}

// ---------------------------------------------------------------------------
// Fused QKV GEMM (round-8 verified version, verbatim)
// ---------------------------------------------------------------------------
struct QkvArgs {
    const __hip_bfloat16* A[3];
    const __hip_bfloat16* W[3];
    const float*          bias[3];
    __hip_bfloat16*       out[3];
};

__global__ __launch_bounds__(256)
void qkv_gemm(QkvArgs args)
{
    __shared__ __hip_bfloat16 S[256][72];

    const int tid  = threadIdx.x;
    const int lane = tid & 63;
    const int wv   = tid >> 6;
    const int wm   = wv >> 1, wn = wv & 1;
    const int l15  = lane & 15, l4 = lane >> 4;
    const int m0   = blockIdx.x * 128;
    const int n0   = blockIdx.y * 128;
    const int z    = blockIdx.z;

    const __hip_bfloat16* __restrict__ A = args.A[z];
    const __hip_bfloat16* __restrict__ W = args.W[z];

    floatx4 acc[4][4] = {};

    for (int k0 = 0; k0 < DMODEL; k0 += 64) {
        #pragma unroll
        for (int it = 0; it < 4; ++it) {
            const int sI   = tid + 256 * it;
            const int row  = sI >> 2;
            const int colq = (sI & 3) * 16;
            const __hip_bfloat16* src = (it < 2)
                ? A + (size_t)(m0 + row) * DMODEL + k0 + colq
                : W + (size_t)(n0 + row - 128) * DMODEL + k0 + colq;
            const uint4* s4 = reinterpret_cast<const uint4*>(src);
            *reinterpret_cast<uint4*>(&S[row][colq])     = s4[0];
            *reinterpret_cast<uint4*>(&S[row][colq + 8]) = s4[1];
        }
        __syncthreads();

        #pragma unroll
        for (int kk = 0; kk < 64; kk += 32) {
            short8 af[4], bf[4];
            #pragma unroll
            for (int mi = 0; mi < 4; ++mi)
                af[mi] = *reinterpret_cast<const short8*>(&S[wm*64 + mi*16 + l15][kk + l4*8]);
            #pragma unroll
            for (int nj = 0; nj < 4; ++nj)
                bf[nj] = *reinterpret_cast<const short8*>(&S[128 + wn*64 + nj*16 + l15][kk + l4*8]);
            #pragma unroll
            for (int mi = 0; mi < 4; ++mi)
                #pragma unroll
                for (int nj = 0; nj < 4; ++nj)
                    acc[mi][nj] = __builtin_amdgcn_mfma_f32_16x16x32_bf16(
                        af[mi], bf[nj], acc[mi][nj], 0, 0, 0);
        }
        __syncthreads();
    }

    const float* bias = args.bias[z];
    __hip_bfloat16* C = args.out[z];
    const bool vt = (z == 2);
    #pragma unroll
    for (int mi = 0; mi < 4; ++mi) {
        const int mbase = m0 + wm*64 + mi*16 + l4*4;
        #pragma unroll
        for (int nj = 0; nj < 4; ++nj) {
            const int nn = n0 + wn*64 + nj*16 + l15;
            const float bb = bias[nn];
            const int h = nn >> 6, d = nn & (HDIM - 1);
            #pragma unroll
            for (int r = 0; r < 4; ++r) {
                const int m = mbase + r;
                const int b = m >> 11, n = m & (NSEQ - 1);
                const float val = acc[mi][nj][r] + bb;
                if (!vt)
                    C[((size_t)(b*NHEAD + h) * NSEQ + n) * HDIM + d] = __float2bfloat16(val);
                else
                    C[((size_t)(b*NHEAD + h) * HDIM + d) * NSEQ + n] = __float2bfloat16(val);
            }
        }
    }
}

// ---------------------------------------------------------------------------
// O-projection GEMM (round-8 version): BM=64, BN=128. f32 output.
// ---------------------------------------------------------------------------
__global__ __launch_bounds__(256)
void oproj_gemm(const __hip_bfloat16* __restrict__ A, const __hip_bfloat16* __restrict__ W,
                const float* __restrict__ bias, float* __restrict__ C)
{
    __shared__ __hip_bfloat16 S[192][72];

    const int tid  = threadIdx.x;
    const int lane = tid & 63;
    const int wv   = tid >> 6;
    const int l15  = lane & 15, l4 = lane >> 4;
    const int m0   = blockIdx.x * 64;
    const int n0   = blockIdx.y * 128;

    floatx4 acc[4][2] = {};

    for (int k0 = 0; k0 < DMODEL; k0 += 64) {
        #pragma unroll
        for (int it = 0; it < 3; ++it) {
            const int sI   = tid + 256 * it;
            const int row  = sI >> 2;
            const int colq = (sI & 3) * 16;
            const __hip_bfloat16* src = (it < 1)
                ? A + (size_t)(m0 + row) * DMODEL + k0 + colq
                : W + (size_t)(n0 + row - 64) * DMODEL + k0 + colq;
            const uint4* s4 = reinterpret_cast<const uint4*>(src);
            *reinterpret_cast<uint4*>(&S[row][colq])     = s4[0];
            *reinterpret_cast<uint4*>(&S[row][colq + 8]) = s4[1];
        }
        __syncthreads();

        #pragma unroll
        for (int kk = 0; kk < 64; kk += 32) {
            short8 af[4], bf[2];
            #pragma unroll
            for (int mi = 0; mi < 4; ++mi)
                af[mi] = *reinterpret_cast<const short8*>(&S[mi*16 + l15][kk + l4*8]);
            #pragma unroll
            for (int nj = 0; nj < 2; ++nj)
                bf[nj] = *reinterpret_cast<const short8*>(&S[64 + wv*32 + nj*16 + l15][kk + l4*8]);
            #pragma unroll
            for (int mi = 0; mi < 4; ++mi)
                #pragma unroll
                for (int nj = 0; nj < 2; ++nj)
                    acc[mi][nj] = __builtin_amdgcn_mfma_f32_16x16x32_bf16(
                        af[mi], bf[nj], acc[mi][nj], 0, 0, 0);
        }
        __syncthreads();
    }

    #pragma unroll
    for (int mi = 0; mi < 4; ++mi) {
        const int mbase = m0 + mi*16 + l4*4;
        #pragma unroll
        for (int nj = 0; nj < 2; ++nj) {
            const int nn = n0 + wv*32 + nj*16 + l15;
            const float bb = bias[nn];
            #pragma unroll
            for (int r = 0; r < 4; ++r)
                C[(size_t)(mbase + r) * DMODEL + nn] = acc[mi][nj][r] + bb;
        }
    }
}

// ---------------------------------------------------------------------------
// Flash attention v11 (round-13 verified, 59.4us): triple-buffered staging,
// single barrier per iteration. Stage(it+2) issued AFTER the barrier; the
// buffer it overwrites was last read in iter it-1 (all waves provably done).
// vmcnt(6) drains stage(it) keeping stage(it+1) in flight. Swapped QK^T,
// cvt_pk P-pack, bias via ds_read_b64, paired q-tiles u/31-u (NT=33).
// ---------------------------------------------------------------------------
__global__ __launch_bounds__(256)
void flash_attn(const __hip_bfloat16* __restrict__ Q,
                const __hip_bfloat16* __restrict__ K,
                const __hip_bfloat16* __restrict__ VT,
                const __hip_bfloat16* __restrict__ Bb,   // bf16 bias * LOG2E
                const int* __restrict__ selfp,
                const int* __restrict__ causalp,
                __hip_bfloat16* __restrict__ Oout)
{
    __shared__ __align__(16) char KB[3][8192];
    __shared__ __align__(16) char VB[3][8192];
    __shared__ __align__(16) char BBUF[3][8192];
    __shared__ __align__(16) char PL[4][2048];   // per-wave P tile [16 q][64 j]

    const int tid  = threadIdx.x;
    const int lane = tid & 63;
    const int wv   = tid >> 6;
    const int l15  = lane & 15, l4 = lane >> 4;

    const int g   = blockIdx.x;
    const int bh  = g & 31;            // g&7 = XCD id
    const int u   = g >> 5;            // [0,16)
    const int qA  = u, qB = 31 - u;
    const int h   = bh & (NHEAD - 1);
    const int b   = bh >> 4;

    const int selfF   = selfp[0];
    const int causalF = causalp[0];
    const bool cz      = (selfF != 0) && (causalF != 0);
    const bool alibiOn = (selfF != 0) && (causalF == 0);
    const float slopeL2 = exp2f(-(8.0f / NHEAD) * (float)(h + 1)) * LOG2E;

    const char* Kh = (const char*)(K  + (size_t)bh * NSEQ * HDIM);
    const char* Vh = (const char*)(VT + (size_t)bh * HDIM * NSEQ);
    const __hip_bfloat16* Qh = Q + (size_t)bh * NSEQ * HDIM;

    const int nA = cz ? (qA + 1) : (NSEQ/64);
    const int NT = cz ? 33 : (NSEQ/32);

    const int qa0 = qA*64 + wv*16, qb0 = qB*64 + wv*16;
    const short8 qfA0 = *(const short8*)&Qh[(qa0 + l15)*HDIM + l4*8];
    const short8 qfA1 = *(const short8*)&Qh[(qa0 + l15)*HDIM + 32 + l4*8];
    const short8 qfB0 = *(const short8*)&Qh[(qb0 + l15)*HDIM + l4*8];
    const short8 qfB1 = *(const short8*)&Qh[(qb0 + l15)*HDIM + 32 + l4*8];
    CFENCE();

    const int srow = lane >> 3;                  // 0..7
    const int co   = (((lane & 7) ^ srow) << 4); // pre-swizzled col byte

    auto stage = [&](int it_, int bi) {
        int qq, jt;
        if (it_ < nA) { qq = qA; jt = it_; } else { qq = qB; jt = it_ - nA; }
        const int j0 = jt << 6;
        const char* Bh = (const char*)Bb + (size_t)qq * 64 * (NSEQ*2);
        #pragma unroll
        for (int i2 = 0; i2 < 2; ++i2) {
            const int rl = wv*16 + i2*8 + srow;
            const int db = (wv*16 + i2*8) * 128;
            gload16(Kh + (size_t)(j0 + rl)*128 + co,          &KB[bi][db]);
            gload16(Vh + (size_t)rl*4096 + (size_t)j0*2 + co, &VB[bi][db]);
            gload16(Bh + (size_t)rl*4096 + (size_t)j0*2 + co, &BBUF[bi][db]);
        }
    };

    char* plw = &PL[wv][l15 * 128];
    const int swq = (l15 & 7) << 4;
    const int rowb = wv*16 + l15;                // lane's q row in bias tile
    const int swb  = (rowb & 7) << 4;

    floatx4 o[4] = {};
    float lr = 0.f;
    short8 qf0 = qfA0, qf1 = qfA1;
    int qbc = qA;

    stage(0, 0);
    CFENCE();
    if (1 < NT) stage(1, 1);
    CFENCE();

    int cb = 0;                 // compute buffer = it % 3
    int sb = 2;                 // stage buffer  = (it+2) % 3
    for (int it = 0; it < NT; ++it) {
        if (it + 1 < NT) {
            asm volatile("s_waitcnt vmcnt(6)" ::: "memory");  // drain stage(it); keep stage(it+1)
        } else {
            asm volatile("s_waitcnt vmcnt(0)" ::: "memory");
        }
        BARRIER();

        if (it + 2 < NT) stage(it + 2, sb);

        const char* kb = KB[cb];
        const char* vb = VB[cb];
        const char* bb = BBUF[cb];

        // ---- QK^T swapped: mfma(K, Q) -> D[row=j=l4*4+r][col=q=l15] ----
        floatx4 s4[4];
        __builtin_amdgcn_s_setprio(1);
        #pragma unroll
        for (int tt = 0; tt < 4; ++tt) {
            const int row = tt*16 + l15;
            const int sw  = (row & 7) << 4;
            const short8 kf0 = *(const short8*)(kb + ((row*128 + l4*16)      ^ sw));
            const short8 kf1 = *(const short8*)(kb + ((row*128 + 64 + l4*16) ^ sw));
            floatx4 z = {};
            z      = __builtin_amdgcn_mfma_f32_16x16x32_bf16(kf0, qf0, z, 0, 0, 0);
            s4[tt] = __builtin_amdgcn_mfma_f32_16x16x32_bf16(kf1, qf1, z, 0, 0, 0);
        }
        __builtin_amdgcn_s_setprio(0);

        // ---- bias from LDS: 4x ds_read_b64 (row = lane's q, 4 consecutive j) ----
        uint2 bl[4];
        #pragma unroll
        for (int tt = 0; tt < 4; ++tt)
            bl[tt] = *(const uint2*)(bb + ((rowb*128 + tt*32 + l4*8) ^ swb));

        // ---- softmax numerator; pack P rows (q=l15) as consecutive-j b64s ----
        const bool domask = cz && (it == nA - 1 || it == NT - 1);
        const int qloc = wv*16 + l15;
        #pragma unroll
        for (int tt = 0; tt < 4; ++tt) {
            float bf[4];
            bf[0] = bf16lo(bl[tt].x); bf[1] = bf16hi(bl[tt].x);
            bf[2] = bf16lo(bl[tt].y); bf[3] = bf16hi(bl[tt].y);
            float e[4];
            #pragma unroll
            for (int r = 0; r < 4; ++r) {
                const int jloc = tt*16 + l4*4 + r;
                float v2 = fmaf(s4[tt][r], 0.125f * LOG2E, bf[r]);
                if (alibiOn) {
                    const int jg = ((it < nA) ? it : it - nA)*64 + jloc;
                    const int dd = jg - (qbc*64 + qloc);
                    if (dd > 0) v2 = fmaf((float)dd, -slopeL2, v2);
                }
                e[r] = __builtin_amdgcn_exp2f(v2);
                if (domask && jloc > qloc) e[r] = 0.0f;
                lr += e[r];
            }
            unsigned p0, p1;
            asm("v_cvt_pk_bf16_f32 %0, %1, %2" : "=v"(p0) : "v"(e[0]), "v"(e[1]));
            asm("v_cvt_pk_bf16_f32 %0, %1, %2" : "=v"(p1) : "v"(e[2]), "v"(e[3]));
            uint2 pw; pw.x = p0; pw.y = p1;
            *(uint2*)(plw + ((tt*32 + l4*8) ^ swq)) = pw;
        }

        // ---- A-frags straight from per-wave P tile (row = l15 = q) ----
        const short8 pf0 = *(const short8*)(plw + ((l4*16)      ^ swq));
        const short8 pf1 = *(const short8*)(plw + ((64 + l4*16) ^ swq));

        // ---- PV from LDS ----
        __builtin_amdgcn_s_setprio(1);
        #pragma unroll
        for (int dt = 0; dt < 4; ++dt) {
            const int row = dt*16 + l15;
            const int sw  = (row & 7) << 4;
            const short8 vf0 = *(const short8*)(vb + ((row*128 + l4*16)      ^ sw));
            const short8 vf1 = *(const short8*)(vb + ((row*128 + 64 + l4*16) ^ sw));
            o[dt] = __builtin_amdgcn_mfma_f32_16x16x32_bf16(pf0, vf0, o[dt], 0, 0, 0);
            o[dt] = __builtin_amdgcn_mfma_f32_16x16x32_bf16(pf1, vf1, o[dt], 0, 0, 0);
        }
        __builtin_amdgcn_s_setprio(0);

        // ---- phase finalize: reduce + write + reset (no LDS; no barrier) ----
        if (it == nA - 1 || it == NT - 1) {
            float t = lr;
            t += __shfl_xor(t, 16);
            t += __shfl_xor(t, 32);
            #pragma unroll
            for (int r = 0; r < 4; ++r) {
                const float lq  = __shfl(t, l4*4 + r);
                const float inv = 1.0f / lq;
                const int n = qbc*64 + wv*16 + l4*4 + r;
                #pragma unroll
                for (int dt = 0; dt < 4; ++dt)
                    Oout[((size_t)(b*NSEQ + n)) * DMODEL + h*HDIM + dt*16 + l15] =
                        __float2bfloat16(o[dt][r] * inv);
            }
            if (it == nA - 1) {
                #pragma unroll
                for (int dt = 0; dt < 4; ++dt) o[dt] = floatx4{0.f, 0.f, 0.f, 0.f};
                lr = 0.f;
                qf0 = qfB0; qf1 = qfB1; qbc = qB;
            }
        }

        cb = (cb == 2) ? 0 : cb + 1;
        sb = (sb == 2) ? 0 : sb + 1;
    }
}

// ---------------------------------------------------------------------------
extern "C" void kernel_launch(void* const* d_in, const int* in_sizes, int n_in,
                              void* d_out, int out_size, void* d_ws, size_t ws_size,
                              hipStream_t stream)
{
    (void)in_sizes; (void)n_in; (void)out_size; (void)ws_size;
    const float* x_q  = (const float*)d_in[0];
    const float* x_kv = (const float*)d_in[1];
    const float* ab   = (const float*)d_in[2];
    const float* Wq   = (const float*)d_in[3];
    const float* bq   = (const float*)d_in[4];
    const float* Wk   = (const float*)d_in[5];
    const float* bk   = (const float*)d_in[6];
    const float* Wv   = (const float*)d_in[7];
    const float* bv   = (const float*)d_in[8];
    const float* Wo   = (const float*)d_in[9];
    const float* bo   = (const float*)d_in[10];
    const int* selfp   = (const int*)d_in[11];
    const int* causalp = (const int*)d_in[12];

    const size_t XB = (size_t)BATCH * NSEQ * DMODEL * sizeof(__hip_bfloat16); // 8 MiB
    const size_t WB = (size_t)DMODEL * DMODEL * sizeof(__hip_bfloat16);       // 2 MiB
    char* ws = (char*)d_ws;
    __hip_bfloat16* xq_b  = (__hip_bfloat16*)(ws);
    __hip_bfloat16* AO    = (__hip_bfloat16*)(ws);                 // alias (xq_b dead)
    __hip_bfloat16* xkv_b = (__hip_bfloat16*)(ws + XB);
    __hip_bfloat16* Wq_b  = (__hip_bfloat16*)(ws + 2*XB);
    __hip_bfloat16* Wk_b  = (__hip_bfloat16*)(ws + 2*XB + WB);
    __hip_bfloat16* Wv_b  = (__hip_bfloat16*)(ws + 2*XB + 2*WB);
    __hip_bfloat16* Wo_b  = (__hip_bfloat16*)(ws + 2*XB + 3*WB);
    __hip_bfloat16* Qb    = (__hip_bfloat16*)(ws + 2*XB + 4*WB);
    __hip_bfloat16* Kb    = (__hip_bfloat16*)(ws + 2*XB + 4*WB + XB);
    __hip_bfloat16* VTb   = (__hip_bfloat16*)(ws + 2*XB + 4*WB + 2*XB);

    // bias bf16 scratch lives in d_out (8 MiB of its 16 MiB); flash reads it,
    // oproj fully overwrites d_out afterwards -> deterministic.
    __hip_bfloat16* ab_b  = (__hip_bfloat16*)d_out;

    cvt_all<<<dim3(2048), dim3(256), 0, stream>>>(
        x_q, x_kv, Wq, Wk, Wv, Wo, ab,
        xq_b, xkv_b, Wq_b, Wk_b, Wv_b, Wo_b, ab_b);

    QkvArgs qa;
    qa.A[0] = xq_b;  qa.A[1] = xkv_b; qa.A[2] = xkv_b;
    qa.W[0] = Wq_b;  qa.W[1] = Wk_b;  qa.W[2] = Wv_b;
    qa.bias[0] = bq; qa.bias[1] = bk; qa.bias[2] = bv;
    qa.out[0] = Qb;  qa.out[1] = Kb;  qa.out[2] = VTb;
    qkv_gemm<<<dim3(32, 8, 3), dim3(256), 0, stream>>>(qa);

    flash_attn<<<dim3(512), dim3(256), 0, stream>>>(
        Qb, Kb, VTb, ab_b, selfp, causalp, AO);

    oproj_gemm<<<dim3(64, 8), dim3(256), 0, stream>>>(AO, Wo_b, bo, (float*)d_out);
}

// Round 18
// 131.231 us; speedup vs baseline: 1.0873x; 1.0023x over previous
//
#include <hip/hip_runtime.h>
#include <hip/hip_bf16.h>

typedef __attribute__((ext_vector_type(8))) short short8;
typedef __attribute__((ext_vector_type(4))) float floatx4;

#define NSEQ   2048
#define DMODEL 1024
#define NHEAD  16
#define HDIM   64
#define BATCH  2
#define LOG2E 1.44269504088896340736f

#define XF4   1048576u     // float4 count per x tensor (2*2048*1024/4) == bias/4
#define WF4   262144u      // float4 count per weight  (1024*1024/4)

__device__ __forceinline__ void gload16(const void* g, void* l) {
    __builtin_amdgcn_global_load_lds(
        (const __attribute__((address_space(1))) void*)g,
        (__attribute__((address_space(3))) void*)l, 16, 0, 0);
}

#define BARRIER() asm volatile("s_barrier" ::: "memory")
#define CFENCE()  asm volatile("" ::: "memory")

__device__ __forceinline__ float bf16lo(unsigned u) {
    union { unsigned i; float f; } c; c.i = u << 16; return c.f;
}
__device__ __forceinline__ float bf16hi(unsigned u) {
    union { unsigned i; float f; } c; c.i = u & 0xffff0000u; return c.f;
}

// ---------------------------------------------------------------------------
// Pre-convert all f32 operands to bf16 in ONE pass (x_q, x_kv, 4 weights,
// and the attention bias scaled by LOG2E). Bias lands in d_out scratch
// (overwritten by oproj afterwards - deterministic, graph-safe).
// ---------------------------------------------------------------------------
__global__ __launch_bounds__(256)
void cvt_all(const float* __restrict__ xq, const float* __restrict__ xkv,
             const float* __restrict__ wq, const float* __restrict__ wk,
             const float* __restrict__ wv, const float* __restrict__ wo,
             const float* __restrict__ bias,
             __hip_bfloat16* __restrict__ dxq, __hip_bfloat16* __restrict__ dxkv,
             __hip_bfloat16* __restrict__ dwq, __hip_bfloat16* __restrict__ dwk,
             __hip_bfloat16* __restrict__ dwv, __hip_bfloat16* __restrict__ dwo,
             __hip_bfloat16* __restrict__ dbias)
{
    const unsigned total = 3*XF4 + 4*WF4;
    const unsigned stride = gridDim.x * blockDim.x;
    for (unsigned i = blockIdx.x*blockDim.x + threadIdx.x; i < total; i += stride) {
        const float4* src; __hip_bfloat16* dst; unsigned off; float sc = 1.0f;
        if (i < XF4)        { src = (const float4*)xq;  dst = dxq;  off = i; }
        else if (i < 2*XF4) { src = (const float4*)xkv; dst = dxkv; off = i - XF4; }
        else if (i < 2*XF4 + 4*WF4) {
            unsigned j = i - 2*XF4; unsigned ws = j >> 18; off = j & (WF4 - 1);
            src = (const float4*)(ws==0 ? wq : ws==1 ? wk : ws==2 ? wv : wo);
            dst = (ws==0 ? dwq : ws==1 ? dwk : ws==2 ? dwv : dwo);
        } else {
            src = (const float4*)bias; dst = dbias; off = i - (2*XF4 + 4*WF4);
            sc = LOG2E;
        }
        float4 v = src[off];
        __hip_bfloat16 h[4] = {__float2bfloat16(v.x * sc), __float2bfloat16(v.y * sc),
                               __float2bfloat16(v.z * sc), __float2bfloat16(v.w * sc)};
        *reinterpret_cast<uint2*>(dst + (size_t)off*4) = *reinterpret_cast<uint2*>(h);
    }
}

// ---------------------------------------------------------------------------
// Fused QKV GEMM (round-8 verified version, verbatim)
// ---------------------------------------------------------------------------
struct QkvArgs {
    const __hip_bfloat16* A[3];
    const __hip_bfloat16* W[3];
    const float*          bias[3];
    __hip_bfloat16*       out[3];
};

__global__ __launch_bounds__(256)
void qkv_gemm(QkvArgs args)
{
    __shared__ __hip_bfloat16 S[256][72];

    const int tid  = threadIdx.x;
    const int lane = tid & 63;
    const int wv   = tid >> 6;
    const int wm   = wv >> 1, wn = wv & 1;
    const int l15  = lane & 15, l4 = lane >> 4;
    const int m0   = blockIdx.x * 128;
    const int n0   = blockIdx.y * 128;
    const int z    = blockIdx.z;

    const __hip_bfloat16* __restrict__ A = args.A[z];
    const __hip_bfloat16* __restrict__ W = args.W[z];

    floatx4 acc[4][4] = {};

    for (int k0 = 0; k0 < DMODEL; k0 += 64) {
        #pragma unroll
        for (int it = 0; it < 4; ++it) {
            const int sI   = tid + 256 * it;
            const int row  = sI >> 2;
            const int colq = (sI & 3) * 16;
            const __hip_bfloat16* src = (it < 2)
                ? A + (size_t)(m0 + row) * DMODEL + k0 + colq
                : W + (size_t)(n0 + row - 128) * DMODEL + k0 + colq;
            const uint4* s4 = reinterpret_cast<const uint4*>(src);
            *reinterpret_cast<uint4*>(&S[row][colq])     = s4[0];
            *reinterpret_cast<uint4*>(&S[row][colq + 8]) = s4[1];
        }
        __syncthreads();

        #pragma unroll
        for (int kk = 0; kk < 64; kk += 32) {
            short8 af[4], bf[4];
            #pragma unroll
            for (int mi = 0; mi < 4; ++mi)
                af[mi] = *reinterpret_cast<const short8*>(&S[wm*64 + mi*16 + l15][kk + l4*8]);
            #pragma unroll
            for (int nj = 0; nj < 4; ++nj)
                bf[nj] = *reinterpret_cast<const short8*>(&S[128 + wn*64 + nj*16 + l15][kk + l4*8]);
            #pragma unroll
            for (int mi = 0; mi < 4; ++mi)
                #pragma unroll
                for (int nj = 0; nj < 4; ++nj)
                    acc[mi][nj] = __builtin_amdgcn_mfma_f32_16x16x32_bf16(
                        af[mi], bf[nj], acc[mi][nj], 0, 0, 0);
        }
        __syncthreads();
    }

    const float* bias = args.bias[z];
    __hip_bfloat16* C = args.out[z];
    const bool vt = (z == 2);
    #pragma unroll
    for (int mi = 0; mi < 4; ++mi) {
        const int mbase = m0 + wm*64 + mi*16 + l4*4;
        #pragma unroll
        for (int nj = 0; nj < 4; ++nj) {
            const int nn = n0 + wn*64 + nj*16 + l15;
            const float bb = bias[nn];
            const int h = nn >> 6, d = nn & (HDIM - 1);
            #pragma unroll
            for (int r = 0; r < 4; ++r) {
                const int m = mbase + r;
                const int b = m >> 11, n = m & (NSEQ - 1);
                const float val = acc[mi][nj][r] + bb;
                if (!vt)
                    C[((size_t)(b*NHEAD + h) * NSEQ + n) * HDIM + d] = __float2bfloat16(val);
                else
                    C[((size_t)(b*NHEAD + h) * HDIM + d) * NSEQ + n] = __float2bfloat16(val);
            }
        }
    }
}

// ---------------------------------------------------------------------------
// O-projection GEMM (round-8 version): BM=64, BN=128. f32 output.
// ---------------------------------------------------------------------------
__global__ __launch_bounds__(256)
void oproj_gemm(const __hip_bfloat16* __restrict__ A, const __hip_bfloat16* __restrict__ W,
                const float* __restrict__ bias, float* __restrict__ C)
{
    __shared__ __hip_bfloat16 S[192][72];

    const int tid  = threadIdx.x;
    const int lane = tid & 63;
    const int wv   = tid >> 6;
    const int l15  = lane & 15, l4 = lane >> 4;
    const int m0   = blockIdx.x * 64;
    const int n0   = blockIdx.y * 128;

    floatx4 acc[4][2] = {};

    for (int k0 = 0; k0 < DMODEL; k0 += 64) {
        #pragma unroll
        for (int it = 0; it < 3; ++it) {
            const int sI   = tid + 256 * it;
            const int row  = sI >> 2;
            const int colq = (sI & 3) * 16;
            const __hip_bfloat16* src = (it < 1)
                ? A + (size_t)(m0 + row) * DMODEL + k0 + colq
                : W + (size_t)(n0 + row - 64) * DMODEL + k0 + colq;
            const uint4* s4 = reinterpret_cast<const uint4*>(src);
            *reinterpret_cast<uint4*>(&S[row][colq])     = s4[0];
            *reinterpret_cast<uint4*>(&S[row][colq + 8]) = s4[1];
        }
        __syncthreads();

        #pragma unroll
        for (int kk = 0; kk < 64; kk += 32) {
            short8 af[4], bf[2];
            #pragma unroll
            for (int mi = 0; mi < 4; ++mi)
                af[mi] = *reinterpret_cast<const short8*>(&S[mi*16 + l15][kk + l4*8]);
            #pragma unroll
            for (int nj = 0; nj < 2; ++nj)
                bf[nj] = *reinterpret_cast<const short8*>(&S[64 + wv*32 + nj*16 + l15][kk + l4*8]);
            #pragma unroll
            for (int mi = 0; mi < 4; ++mi)
                #pragma unroll
                for (int nj = 0; nj < 2; ++nj)
                    acc[mi][nj] = __builtin_amdgcn_mfma_f32_16x16x32_bf16(
                        af[mi], bf[nj], acc[mi][nj], 0, 0, 0);
        }
        __syncthreads();
    }

    #pragma unroll
    for (int mi = 0; mi < 4; ++mi) {
        const int mbase = m0 + mi*16 + l4*4;
        #pragma unroll
        for (int nj = 0; nj < 2; ++nj) {
            const int nn = n0 + wv*32 + nj*16 + l15;
            const float bb = bias[nn];
            #pragma unroll
            for (int r = 0; r < 4; ++r)
                C[(size_t)(mbase + r) * DMODEL + nn] = acc[mi][nj][r] + bb;
        }
    }
}

// ---------------------------------------------------------------------------
// Flash attention v11 (round-13/16 verified, 59.5us): triple-buffered staging,
// single barrier per iteration. Stage(it+2) issued AFTER the barrier; the
// buffer it overwrites was last read in iter it-1 (all waves provably done).
// vmcnt(6) drains stage(it) keeping stage(it+1) in flight. Swapped QK^T,
// cvt_pk P-pack, bias via ds_read_b64, paired q-tiles u/31-u (NT=33).
// ---------------------------------------------------------------------------
__global__ __launch_bounds__(256)
void flash_attn(const __hip_bfloat16* __restrict__ Q,
                const __hip_bfloat16* __restrict__ K,
                const __hip_bfloat16* __restrict__ VT,
                const __hip_bfloat16* __restrict__ Bb,   // bf16 bias * LOG2E
                const int* __restrict__ selfp,
                const int* __restrict__ causalp,
                __hip_bfloat16* __restrict__ Oout)
{
    __shared__ __align__(16) char KB[3][8192];
    __shared__ __align__(16) char VB[3][8192];
    __shared__ __align__(16) char BBUF[3][8192];
    __shared__ __align__(16) char PL[4][2048];   // per-wave P tile [16 q][64 j]

    const int tid  = threadIdx.x;
    const int lane = tid & 63;
    const int wv   = tid >> 6;
    const int l15  = lane & 15, l4 = lane >> 4;

    const int g   = blockIdx.x;
    const int bh  = g & 31;            // g&7 = XCD id
    const int u   = g >> 5;            // [0,16)
    const int qA  = u, qB = 31 - u;
    const int h   = bh & (NHEAD - 1);
    const int b   = bh >> 4;

    const int selfF   = selfp[0];
    const int causalF = causalp[0];
    const bool cz      = (selfF != 0) && (causalF != 0);
    const bool alibiOn = (selfF != 0) && (causalF == 0);
    const float slopeL2 = exp2f(-(8.0f / NHEAD) * (float)(h + 1)) * LOG2E;

    const char* Kh = (const char*)(K  + (size_t)bh * NSEQ * HDIM);
    const char* Vh = (const char*)(VT + (size_t)bh * HDIM * NSEQ);
    const __hip_bfloat16* Qh = Q + (size_t)bh * NSEQ * HDIM;

    const int nA = cz ? (qA + 1) : (NSEQ/64);
    const int NT = cz ? 33 : (NSEQ/32);

    const int qa0 = qA*64 + wv*16, qb0 = qB*64 + wv*16;
    const short8 qfA0 = *(const short8*)&Qh[(qa0 + l15)*HDIM + l4*8];
    const short8 qfA1 = *(const short8*)&Qh[(qa0 + l15)*HDIM + 32 + l4*8];
    const short8 qfB0 = *(const short8*)&Qh[(qb0 + l15)*HDIM + l4*8];
    const short8 qfB1 = *(const short8*)&Qh[(qb0 + l15)*HDIM + 32 + l4*8];
    CFENCE();

    const int srow = lane >> 3;                  // 0..7
    const int co   = (((lane & 7) ^ srow) << 4); // pre-swizzled col byte

    auto stage = [&](int it_, int bi) {
        int qq, jt;
        if (it_ < nA) { qq = qA; jt = it_; } else { qq = qB; jt = it_ - nA; }
        const int j0 = jt << 6;
        const char* Bh = (const char*)Bb + (size_t)qq * 64 * (NSEQ*2);
        #pragma unroll
        for (int i2 = 0; i2 < 2; ++i2) {
            const int rl = wv*16 + i2*8 + srow;
            const int db = (wv*16 + i2*8) * 128;
            gload16(Kh + (size_t)(j0 + rl)*128 + co,          &KB[bi][db]);
            gload16(Vh + (size_t)rl*4096 + (size_t)j0*2 + co, &VB[bi][db]);
            gload16(Bh + (size_t)rl*4096 + (size_t)j0*2 + co, &BBUF[bi][db]);
        }
    };

    char* plw = &PL[wv][l15 * 128];
    const int swq = (l15 & 7) << 4;
    const int rowb = wv*16 + l15;                // lane's q row in bias tile
    const int swb  = (rowb & 7) << 4;

    floatx4 o[4] = {};
    float lr = 0.f;
    short8 qf0 = qfA0, qf1 = qfA1;
    int qbc = qA;

    stage(0, 0);
    CFENCE();
    if (1 < NT) stage(1, 1);
    CFENCE();

    int cb = 0;                 // compute buffer = it % 3
    int sb = 2;                 // stage buffer  = (it+2) % 3
    for (int it = 0; it < NT; ++it) {
        if (it + 1 < NT) {
            asm volatile("s_waitcnt vmcnt(6)" ::: "memory");  // drain stage(it); keep stage(it+1)
        } else {
            asm volatile("s_waitcnt vmcnt(0)" ::: "memory");
        }
        BARRIER();

        if (it + 2 < NT) stage(it + 2, sb);

        const char* kb = KB[cb];
        const char* vb = VB[cb];
        const char* bb = BBUF[cb];

        // ---- QK^T swapped: mfma(K, Q) -> D[row=j=l4*4+r][col=q=l15] ----
        floatx4 s4[4];
        __builtin_amdgcn_s_setprio(1);
        #pragma unroll
        for (int tt = 0; tt < 4; ++tt) {
            const int row = tt*16 + l15;
            const int sw  = (row & 7) << 4;
            const short8 kf0 = *(const short8*)(kb + ((row*128 + l4*16)      ^ sw));
            const short8 kf1 = *(const short8*)(kb + ((row*128 + 64 + l4*16) ^ sw));
            floatx4 z = {};
            z      = __builtin_amdgcn_mfma_f32_16x16x32_bf16(kf0, qf0, z, 0, 0, 0);
            s4[tt] = __builtin_amdgcn_mfma_f32_16x16x32_bf16(kf1, qf1, z, 0, 0, 0);
        }
        __builtin_amdgcn_s_setprio(0);

        // ---- bias from LDS: 4x ds_read_b64 (row = lane's q, 4 consecutive j) ----
        uint2 bl[4];
        #pragma unroll
        for (int tt = 0; tt < 4; ++tt)
            bl[tt] = *(const uint2*)(bb + ((rowb*128 + tt*32 + l4*8) ^ swb));

        // ---- softmax numerator; pack P rows (q=l15) as consecutive-j b64s ----
        const bool domask = cz && (it == nA - 1 || it == NT - 1);
        const int qloc = wv*16 + l15;
        #pragma unroll
        for (int tt = 0; tt < 4; ++tt) {
            float bf[4];
            bf[0] = bf16lo(bl[tt].x); bf[1] = bf16hi(bl[tt].x);
            bf[2] = bf16lo(bl[tt].y); bf[3] = bf16hi(bl[tt].y);
            float e[4];
            #pragma unroll
            for (int r = 0; r < 4; ++r) {
                const int jloc = tt*16 + l4*4 + r;
                float v2 = fmaf(s4[tt][r], 0.125f * LOG2E, bf[r]);
                if (alibiOn) {
                    const int jg = ((it < nA) ? it : it - nA)*64 + jloc;
                    const int dd = jg - (qbc*64 + qloc);
                    if (dd > 0) v2 = fmaf((float)dd, -slopeL2, v2);
                }
                e[r] = __builtin_amdgcn_exp2f(v2);
                if (domask && jloc > qloc) e[r] = 0.0f;
                lr += e[r];
            }
            unsigned p0, p1;
            asm("v_cvt_pk_bf16_f32 %0, %1, %2" : "=v"(p0) : "v"(e[0]), "v"(e[1]));
            asm("v_cvt_pk_bf16_f32 %0, %1, %2" : "=v"(p1) : "v"(e[2]), "v"(e[3]));
            uint2 pw; pw.x = p0; pw.y = p1;
            *(uint2*)(plw + ((tt*32 + l4*8) ^ swq)) = pw;
        }

        // ---- A-frags straight from per-wave P tile (row = l15 = q) ----
        const short8 pf0 = *(const short8*)(plw + ((l4*16)      ^ swq));
        const short8 pf1 = *(const short8*)(plw + ((64 + l4*16) ^ swq));

        // ---- PV from LDS ----
        __builtin_amdgcn_s_setprio(1);
        #pragma unroll
        for (int dt = 0; dt < 4; ++dt) {
            const int row = dt*16 + l15;
            const int sw  = (row & 7) << 4;
            const short8 vf0 = *(const short8*)(vb + ((row*128 + l4*16)      ^ sw));
            const short8 vf1 = *(const short8*)(vb + ((row*128 + 64 + l4*16) ^ sw));
            o[dt] = __builtin_amdgcn_mfma_f32_16x16x32_bf16(pf0, vf0, o[dt], 0, 0, 0);
            o[dt] = __builtin_amdgcn_mfma_f32_16x16x32_bf16(pf1, vf1, o[dt], 0, 0, 0);
        }
        __builtin_amdgcn_s_setprio(0);

        // ---- phase finalize: reduce + write + reset (no LDS; no barrier) ----
        if (it == nA - 1 || it == NT - 1) {
            float t = lr;
            t += __shfl_xor(t, 16);
            t += __shfl_xor(t, 32);
            #pragma unroll
            for (int r = 0; r < 4; ++r) {
                const float lq  = __shfl(t, l4*4 + r);
                const float inv = 1.0f / lq;
                const int n = qbc*64 + wv*16 + l4*4 + r;
                #pragma unroll
                for (int dt = 0; dt < 4; ++dt)
                    Oout[((size_t)(b*NSEQ + n)) * DMODEL + h*HDIM + dt*16 + l15] =
                        __float2bfloat16(o[dt][r] * inv);
            }
            if (it == nA - 1) {
                #pragma unroll
                for (int dt = 0; dt < 4; ++dt) o[dt] = floatx4{0.f, 0.f, 0.f, 0.f};
                lr = 0.f;
                qf0 = qfB0; qf1 = qfB1; qbc = qB;
            }
        }

        cb = (cb == 2) ? 0 : cb + 1;
        sb = (sb == 2) ? 0 : sb + 1;
    }
}

// ---------------------------------------------------------------------------
extern "C" void kernel_launch(void* const* d_in, const int* in_sizes, int n_in,
                              void* d_out, int out_size, void* d_ws, size_t ws_size,
                              hipStream_t stream)
{
    (void)in_sizes; (void)n_in; (void)out_size; (void)ws_size;
    const float* x_q  = (const float*)d_in[0];
    const float* x_kv = (const float*)d_in[1];
    const float* ab   = (const float*)d_in[2];
    const float* Wq   = (const float*)d_in[3];
    const float* bq   = (const float*)d_in[4];
    const float* Wk   = (const float*)d_in[5];
    const float* bk   = (const float*)d_in[6];
    const float* Wv   = (const float*)d_in[7];
    const float* bv   = (const float*)d_in[8];
    const float* Wo   = (const float*)d_in[9];
    const float* bo   = (const float*)d_in[10];
    const int* selfp   = (const int*)d_in[11];
    const int* causalp = (const int*)d_in[12];

    const size_t XB = (size_t)BATCH * NSEQ * DMODEL * sizeof(__hip_bfloat16); // 8 MiB
    const size_t WB = (size_t)DMODEL * DMODEL * sizeof(__hip_bfloat16);       // 2 MiB
    char* ws = (char*)d_ws;
    __hip_bfloat16* xq_b  = (__hip_bfloat16*)(ws);
    __hip_bfloat16* AO    = (__hip_bfloat16*)(ws);                 // alias (xq_b dead)
    __hip_bfloat16* xkv_b = (__hip_bfloat16*)(ws + XB);
    __hip_bfloat16* Wq_b  = (__hip_bfloat16*)(ws + 2*XB);
    __hip_bfloat16* Wk_b  = (__hip_bfloat16*)(ws + 2*XB + WB);
    __hip_bfloat16* Wv_b  = (__hip_bfloat16*)(ws + 2*XB + 2*WB);
    __hip_bfloat16* Wo_b  = (__hip_bfloat16*)(ws + 2*XB + 3*WB);
    __hip_bfloat16* Qb    = (__hip_bfloat16*)(ws + 2*XB + 4*WB);
    __hip_bfloat16* Kb    = (__hip_bfloat16*)(ws + 2*XB + 4*WB + XB);
    __hip_bfloat16* VTb   = (__hip_bfloat16*)(ws + 2*XB + 4*WB + 2*XB);

    // bias bf16 scratch lives in d_out (8 MiB of its 16 MiB); flash reads it,
    // oproj fully overwrites d_out afterwards -> deterministic.
    __hip_bfloat16* ab_b  = (__hip_bfloat16*)d_out;

    cvt_all<<<dim3(2048), dim3(256), 0, stream>>>(
        x_q, x_kv, Wq, Wk, Wv, Wo, ab,
        xq_b, xkv_b, Wq_b, Wk_b, Wv_b, Wo_b, ab_b);

    QkvArgs qa;
    qa.A[0] = xq_b;  qa.A[1] = xkv_b; qa.A[2] = xkv_b;
    qa.W[0] = Wq_b;  qa.W[1] = Wk_b;  qa.W[2] = Wv_b;
    qa.bias[0] = bq; qa.bias[1] = bk; qa.bias[2] = bv;
    qa.out[0] = Qb;  qa.out[1] = Kb;  qa.out[2] = VTb;
    qkv_gemm<<<dim3(32, 8, 3), dim3(256), 0, stream>>>(qa);

    flash_attn<<<dim3(512), dim3(256), 0, stream>>>(
        Qb, Kb, VTb, ab_b, selfp, causalp, AO);

    oproj_gemm<<<dim3(64, 8), dim3(256), 0, stream>>>(AO, Wo_b, bo, (float*)d_out);
}